// Round 9
// baseline (160.998 us; speedup 1.0000x reference)
//
#include <hip/hip_runtime.h>
#include <hip/hip_bf16.h>

// B=8, N=4096, F_IN=F_OUT=256, E=131072
// out = (adj_norm @ X) @ W + bias  (reassociated; same math as ref).
// adj[src,dst]=1 (dups collapse), deg = (#distinct nbrs) + 1e-6.
// 3-dispatch pipeline: prep -> build_list -> fused agg+gemm.
// R8: the inline-asm vmcnt pipeline (R6) crashed on hardware; R2/R3/R5
// showed source-level pipelining is always re-serialized.  Axis closed.
// This round runs the CLEAN geometry experiment R2 confounded: NPB=16
// (grid 2048 = 8 blocks/CU = 32 waves/CU) with the R1 gather body VERBATIM
// (scalar u16 list reads, 4 rows in flight, VGPR ~60 preserved).  R2's
// regression came from its rewritten list-read (VGPR 40 -> loads
// serialized), not from the geometry.  Phase B = R2's verified 1-m-tile
// gemm.  Both halves independently harness-verified at absmax 0.0078125.

#define GC_B     8
#define GC_N     4096
#define GC_F     256
#define GC_E     131072
#define GC_M     (GC_B * GC_N)          // 32768
#define MASK_WPR (GC_N / 32)            // 128 words / row (512 B)
#define LIST_CAP 128                    // deg ~ Poisson(32); P(>=128) ~ 0
#define NPB      16                     // nodes per fused block

typedef __attribute__((ext_vector_type(8))) short         short8;   // 8 x bf16
typedef __attribute__((ext_vector_type(2))) float         float2v;
typedef __attribute__((ext_vector_type(4))) float         float4v;
typedef __attribute__((ext_vector_type(4))) unsigned int  uint4v;

static __device__ __forceinline__ unsigned short f2bf_rne(float f) {
    unsigned u = __builtin_bit_cast(unsigned, f);
    u += 0x7fffu + ((u >> 16) & 1u);
    return (unsigned short)(u >> 16);
}

// Accumulate a u32 (two packed bf16) into a float2 accumulator with ONE shl +
// ONE pk_add:  .x += exact lo-bf16 (low bits zeroed by shift);
//              .y += hi-bf16 with lo bits as mantissa garbage (<= 2^-7 rel,
//                    same order as bf16 quantization; absmax budget has 6x
//                    headroom vs threshold).
static __device__ __forceinline__ float2v bfpair(unsigned v) {
    return (float2v){__builtin_bit_cast(float, v << 16),
                     __builtin_bit_cast(float, v)};
}

// ---------------------------------------------------------------------------
// Kernel 1: prep — fused independent setup, block-role split:
//   [0,4096)    : X fp32 -> Xb bf16 (8 elems/thread, 16B stores)
//   [4096,4352) : Wt[n][k] = bf16(W[k][n])
//   [4352,4480) : zero mask (2 MiB)
//   [4480]      : zero cnt  (16 KiB)
// ---------------------------------------------------------------------------
__global__ __launch_bounds__(256) void prep_kernel(
        const float* __restrict__ X, const float* __restrict__ W,
        unsigned short* __restrict__ Xb, unsigned short* __restrict__ Wt,
        unsigned* __restrict__ mask, unsigned* __restrict__ cnt) {
    const int blk = blockIdx.x;
    const int t   = threadIdx.x;
    if (blk < 4096) {
        const size_t i = ((size_t)blk * 256 + t) * 8;
        const float4v v0 = *(const float4v*)(X + i);
        const float4v v1 = *(const float4v*)(X + i + 4);
        union { unsigned short h[8]; short8 s; } u;
        u.h[0] = f2bf_rne(v0[0]); u.h[1] = f2bf_rne(v0[1]);
        u.h[2] = f2bf_rne(v0[2]); u.h[3] = f2bf_rne(v0[3]);
        u.h[4] = f2bf_rne(v1[0]); u.h[5] = f2bf_rne(v1[1]);
        u.h[6] = f2bf_rne(v1[2]); u.h[7] = f2bf_rne(v1[3]);
        *(short8*)(Xb + i) = u.s;
    } else if (blk < 4352) {
        const int n = blk - 4096;
        Wt[n * GC_F + t] = f2bf_rne(W[t * GC_F + n]);
    } else if (blk < 4480) {
        const size_t base = ((size_t)(blk - 4352) * 256 + t) * 4;
        const uint4v z = {0, 0, 0, 0};
        #pragma unroll
        for (int j = 0; j < 4; j++) ((uint4v*)mask)[base + j] = z;
    } else {
        const uint4v z = {0, 0, 0, 0};
        #pragma unroll
        for (int j = 0; j < 4; j++) ((uint4v*)cnt)[(size_t)t * 4 + j] = z;
    }
}

// ---------------------------------------------------------------------------
// Kernel 2: dedup + list build in ONE pass (atomicOr old value: first setter
// of a bit appends). List order nondeterministic; fp32 reorder is ulp-noise.
// ---------------------------------------------------------------------------
__global__ void build_list_kernel(const int* __restrict__ ei,
                                  unsigned* __restrict__ mask,
                                  unsigned* __restrict__ cnt,
                                  unsigned short* __restrict__ list) {
    const int e = blockIdx.x * blockDim.x + threadIdx.x;
    if (e < GC_E) {
        const int s = ei[e];
        const int d = ei[GC_E + e];
        const unsigned bit = 1u << (d & 31);
        const unsigned old = atomicOr(&mask[s * MASK_WPR + (d >> 5)], bit);
        if (!(old & bit)) {
            const unsigned p = atomicAdd(&cnt[s], 1u);
            if (p < LIST_CAP) list[s * LIST_CAP + p] = (unsigned short)d;
        }
    }
}

// ---------------------------------------------------------------------------
// Kernel 3: FUSED aggregate + gemm.  Block = 16 nodes of ONE batch.
//   grid 2048 = 8 b (XCD-pinned, blk&7) x 256 node-groups; up to 8 blocks/CU
//   (LDS 12.3 KiB, VGPR ~60) = 32 waves/CU — 2x the R1 TLP, with the R1
//   per-wave gather body UNCHANGED (4 rows in flight preserved).
//
// Phase A (aggregate): wave w owns nodes w*4..w*4+3 sequentially; lane split
//   fg=lane&31 (8 feats, 16B), ks=lane>>5 (2 slots).  4 accumulator banks,
//   garbage-mantissa unpack, shfl_xor(32) fold.  Gather loop VERBATIM R1
//   (scalar u16 list reads -> 4 independent uint4 loads per group).
//   Epilogue writes bf16 rows straight into LDS in MFMA-frag layout with
//   the r^(chunk&15) slot swizzle (conflict-free write and read).
//
// Phase B (gemm): wave w owns feats w*64..+63 (4 f-tiles x 1 m-tile) —
//   R2's verified structure.  wfr (Wt frags) for ft=0 hoisted ABOVE the
//   barrier; out written nontemporal (keeps Xb/Wt L2-resident).
// ---------------------------------------------------------------------------
__global__ __launch_bounds__(256, 4) void agg_gemm_kernel(
        const unsigned short* __restrict__ Xb, const unsigned* __restrict__ cnt,
        const unsigned short* __restrict__ list,
        const unsigned short* __restrict__ Wt,
        const float* __restrict__ bias, float* __restrict__ out) {
    __shared__ __attribute__((aligned(16))) uint4v lstv[NPB * LIST_CAP / 8]; // 4 KiB
    __shared__ int degs[NPB];
    __shared__ __attribute__((aligned(16))) uint4v frag[NPB * GC_F / 8];     // 8 KiB

    const int tid  = threadIdx.x;
    const int w    = tid >> 6;
    const int lane = tid & 63;
    const int b    = blockIdx.x & 7;              // XCD-pinned batch
    const int n0   = (blockIdx.x >> 3) * NPB;     // first node of group

    // stage 16 neighbor lists (4 KiB = 256 x uint4, one per thread) + degrees
    lstv[tid] = ((const uint4v*)(list + (size_t)n0 * LIST_CAP))[tid];
    if (tid < NPB) {
        const unsigned c = cnt[n0 + tid];
        degs[tid] = (int)(c < LIST_CAP ? c : LIST_CAP);
    }
    __syncthreads();

    const unsigned short* lst = (const unsigned short*)lstv;
    const int fg = lane & 31;               // feature group (8 feats, 16B)
    const int ks = lane >> 5;               // neighbor slot 0..1
    const unsigned short* xbase = Xb + ((size_t)b << 20) + fg * 8;

    #pragma unroll 1
    for (int it = 0; it < NPB / 4; ++it) {
        const int t   = w * 4 + it;         // local node 0..15
        const int deg = degs[t];
        const unsigned short* tl = lst + t * LIST_CAP;

        float2v a0[4] = {}, a1[4] = {}, a2[4] = {}, a3[4] = {};
        int k = ks;
        for (; k + 6 < deg; k += 8) {       // VERBATIM R1 gather group
            const unsigned o0 = (unsigned)tl[k]     << 8;
            const unsigned o1 = (unsigned)tl[k + 2] << 8;
            const unsigned o2 = (unsigned)tl[k + 4] << 8;
            const unsigned o3 = (unsigned)tl[k + 6] << 8;
            const uint4v v0 = *(const uint4v*)(xbase + o0);
            const uint4v v1 = *(const uint4v*)(xbase + o1);
            const uint4v v2 = *(const uint4v*)(xbase + o2);
            const uint4v v3 = *(const uint4v*)(xbase + o3);
            #pragma unroll
            for (int e = 0; e < 4; e++) {
                a0[e] += bfpair(v0[e]);
                a1[e] += bfpair(v1[e]);
                a2[e] += bfpair(v2[e]);
                a3[e] += bfpair(v3[e]);
            }
        }
        for (; k < deg; k += 2) {           // singles tail -> bank 0 (as R1)
            const uint4v v0 = *(const uint4v*)(xbase + ((unsigned)tl[k] << 8));
            #pragma unroll
            for (int e = 0; e < 4; e++) a0[e] += bfpair(v0[e]);
        }

        float accv[8];
        #pragma unroll
        for (int e = 0; e < 4; e++) {
            const float2v s = (a0[e] + a1[e]) + (a2[e] + a3[e]);
            accv[2 * e]     = s.x;   // lo bf16 feature (exact)
            accv[2 * e + 1] = s.y;   // hi bf16 feature (garbage-mantissa)
        }
        #pragma unroll
        for (int e = 0; e < 8; e++)
            accv[e] += __shfl_xor(accv[e], 32, 64);   // fold slot 1 -> slot 0

        if (ks == 0) {
            const float inv = 1.0f / ((float)deg + 1e-6f);
            uint4v o;
            #pragma unroll
            for (int e = 0; e < 4; e++) {
                const float s0 = accv[2 * e] * inv;
                const float s1 = accv[2 * e + 1] * inv;
                o[e] = (unsigned)f2bf_rne(s0) | ((unsigned)f2bf_rne(s1) << 16);
            }
            // frag layout: [chunk=fg][slot = row ^ (fg&15)] of 16B units
            frag[fg * 16 + (t ^ (fg & 15))] = o;
        }
    }

    // hoist ft=0 Wt frags above the barrier (no LDS dependency)
    const int r     = lane & 15;
    const int q     = lane >> 4;
    const int fbase = w * 64;                     // wave: 64 output feats
    short8 wfr[8];
    {
        const unsigned short* wp = Wt + (size_t)(fbase + r) * GC_F + q * 8;
        #pragma unroll
        for (int kc = 0; kc < 8; kc++) wfr[kc] = *(const short8*)(wp + kc * 32);
    }
    __syncthreads();

    const size_t orow0 = ((size_t)b << 12) + n0;  // first out row
    const unsigned short* fragb = (const unsigned short*)frag;
    #pragma unroll 1
    for (int ft = 0; ft < 4; ++ft) {
        const int f0 = fbase + ft * 16;
        const float4v bv = *(const float4v*)(bias + f0 + 4 * q);
        short8 afr[8];
        #pragma unroll
        for (int kc = 0; kc < 8; kc++) {
            const int ch = 4 * kc + q;
            afr[kc] = *(const short8*)(fragb + ch * 128 + (r ^ (ch & 15)) * 8);
        }
        float4v acc = {0, 0, 0, 0};
        #pragma unroll
        for (int kc = 0; kc < 8; kc++)
            acc = __builtin_amdgcn_mfma_f32_16x16x32_bf16(
                wfr[kc], afr[kc], acc, 0, 0, 0);
        const float4v res = acc + bv;
        __builtin_nontemporal_store(res,
            (float4v*)(out + (orow0 + r) * GC_F + f0 + 4 * q));
        if (ft < 3) {   // reload wfr for next f-tile (after last use)
            const unsigned short* wp = Wt + (size_t)(f0 + 16 + r) * GC_F + q * 8;
            #pragma unroll
            for (int kc = 0; kc < 8; kc++) wfr[kc] = *(const short8*)(wp + kc * 32);
        }
    }
}

// ---------------------------------------------------------------------------
extern "C" void kernel_launch(void* const* d_in, const int* in_sizes, int n_in,
                              void* d_out, int out_size, void* d_ws, size_t ws_size,
                              hipStream_t stream) {
    const float* x      = (const float*)d_in[0];   // (8, 4096, 256)
    const int*   ei     = (const int*)d_in[1];     // (2, 131072)
    const float* weight = (const float*)d_in[2];   // (256, 256)
    const float* bias   = (const float*)d_in[3];   // (256,)
    float*       out    = (float*)d_out;           // (8, 4096, 256)

    // ws layout (~19.1 MiB):
    //   [ Xb 16Mi ][ Wt 128Ki ][ mask 2Mi ][ cnt 16Ki ][ list 1Mi ]
    char* p = (char*)d_ws;
    unsigned short* Xb   = (unsigned short*)p;             p += (size_t)GC_M * GC_F * 2;
    unsigned short* Wt   = (unsigned short*)p;             p += (size_t)GC_F * GC_F * 2;
    unsigned*       mask = (unsigned*)p;                   p += (size_t)GC_N * MASK_WPR * 4;
    unsigned*       cnt  = (unsigned*)p;                   p += (size_t)GC_N * 4;
    unsigned short* list = (unsigned short*)p;

    prep_kernel<<<4481, 256, 0, stream>>>(x, weight, Xb, Wt, mask, cnt);

    build_list_kernel<<<(GC_E + 255) / 256, 256, 0, stream>>>(ei, mask, cnt, list);

    agg_gemm_kernel<<<GC_M / NPB, 256, 0, stream>>>(
        Xb, cnt, list, Wt, bias, out);
}

// Round 10
// 160.975 us; speedup vs baseline: 1.0001x; 1.0001x over previous
//
#include <hip/hip_runtime.h>
#include <hip/hip_bf16.h>

// B=8, N=4096, F_IN=F_OUT=256, E=131072
// out = (adj_norm @ X) @ W + bias  (reassociated; same math as ref).
// adj[src,dst]=1 (dups collapse), deg = (#distinct nbrs) + 1e-6.
// 3-dispatch pipeline: prep -> build_list -> fused agg+gemm.
// R9: R8 isolated the true cause of the NPB=16 regressions: the register
// allocator's occupancy heuristic.  With LDS small enough for >8 blocks/CU
// it squeezes VGPR 60->40 (targeting ~12 waves/SIMD) and serializes the
// gather to ~2 loads in flight (-35% per-wave).  Fix: keep NPB=16 geometry
// (grid 2048 = 8 blocks/CU) but declare amdgpu_waves_per_eu(4, 8) — the
// MAX=8 removes any incentive to allocate below 64 VGPR, preserving the
// R1 4-in-flight gather body at 2x R1's resident waves.  Body and phase B
// are bit-for-bit R8 (harness-verified, absmax 0.0078125).

#define GC_B     8
#define GC_N     4096
#define GC_F     256
#define GC_E     131072
#define GC_M     (GC_B * GC_N)          // 32768
#define MASK_WPR (GC_N / 32)            // 128 words / row (512 B)
#define LIST_CAP 128                    // deg ~ Poisson(32); P(>=128) ~ 0
#define NPB      16                     // nodes per fused block

typedef __attribute__((ext_vector_type(8))) short         short8;   // 8 x bf16
typedef __attribute__((ext_vector_type(2))) float         float2v;
typedef __attribute__((ext_vector_type(4))) float         float4v;
typedef __attribute__((ext_vector_type(4))) unsigned int  uint4v;

static __device__ __forceinline__ unsigned short f2bf_rne(float f) {
    unsigned u = __builtin_bit_cast(unsigned, f);
    u += 0x7fffu + ((u >> 16) & 1u);
    return (unsigned short)(u >> 16);
}

// Accumulate a u32 (two packed bf16) into a float2 accumulator with ONE shl +
// ONE pk_add:  .x += exact lo-bf16 (low bits zeroed by shift);
//              .y += hi-bf16 with lo bits as mantissa garbage (<= 2^-7 rel,
//                    same order as bf16 quantization; absmax budget has 6x
//                    headroom vs threshold).
static __device__ __forceinline__ float2v bfpair(unsigned v) {
    return (float2v){__builtin_bit_cast(float, v << 16),
                     __builtin_bit_cast(float, v)};
}

// ---------------------------------------------------------------------------
// Kernel 1: prep — fused independent setup, block-role split:
//   [0,4096)    : X fp32 -> Xb bf16 (8 elems/thread, 16B stores)
//   [4096,4352) : Wt[n][k] = bf16(W[k][n])
//   [4352,4480) : zero mask (2 MiB)
//   [4480]      : zero cnt  (16 KiB)
// ---------------------------------------------------------------------------
__global__ __launch_bounds__(256) void prep_kernel(
        const float* __restrict__ X, const float* __restrict__ W,
        unsigned short* __restrict__ Xb, unsigned short* __restrict__ Wt,
        unsigned* __restrict__ mask, unsigned* __restrict__ cnt) {
    const int blk = blockIdx.x;
    const int t   = threadIdx.x;
    if (blk < 4096) {
        const size_t i = ((size_t)blk * 256 + t) * 8;
        const float4v v0 = *(const float4v*)(X + i);
        const float4v v1 = *(const float4v*)(X + i + 4);
        union { unsigned short h[8]; short8 s; } u;
        u.h[0] = f2bf_rne(v0[0]); u.h[1] = f2bf_rne(v0[1]);
        u.h[2] = f2bf_rne(v0[2]); u.h[3] = f2bf_rne(v0[3]);
        u.h[4] = f2bf_rne(v1[0]); u.h[5] = f2bf_rne(v1[1]);
        u.h[6] = f2bf_rne(v1[2]); u.h[7] = f2bf_rne(v1[3]);
        *(short8*)(Xb + i) = u.s;
    } else if (blk < 4352) {
        const int n = blk - 4096;
        Wt[n * GC_F + t] = f2bf_rne(W[t * GC_F + n]);
    } else if (blk < 4480) {
        const size_t base = ((size_t)(blk - 4352) * 256 + t) * 4;
        const uint4v z = {0, 0, 0, 0};
        #pragma unroll
        for (int j = 0; j < 4; j++) ((uint4v*)mask)[base + j] = z;
    } else {
        const uint4v z = {0, 0, 0, 0};
        #pragma unroll
        for (int j = 0; j < 4; j++) ((uint4v*)cnt)[(size_t)t * 4 + j] = z;
    }
}

// ---------------------------------------------------------------------------
// Kernel 2: dedup + list build in ONE pass (atomicOr old value: first setter
// of a bit appends). List order nondeterministic; fp32 reorder is ulp-noise.
// ---------------------------------------------------------------------------
__global__ void build_list_kernel(const int* __restrict__ ei,
                                  unsigned* __restrict__ mask,
                                  unsigned* __restrict__ cnt,
                                  unsigned short* __restrict__ list) {
    const int e = blockIdx.x * blockDim.x + threadIdx.x;
    if (e < GC_E) {
        const int s = ei[e];
        const int d = ei[GC_E + e];
        const unsigned bit = 1u << (d & 31);
        const unsigned old = atomicOr(&mask[s * MASK_WPR + (d >> 5)], bit);
        if (!(old & bit)) {
            const unsigned p = atomicAdd(&cnt[s], 1u);
            if (p < LIST_CAP) list[s * LIST_CAP + p] = (unsigned short)d;
        }
    }
}

// ---------------------------------------------------------------------------
// Kernel 3: FUSED aggregate + gemm.  Block = 16 nodes of ONE batch.
//   grid 2048 = 8 b (XCD-pinned, blk&7) x 256 node-groups; 8 blocks/CU
//   (LDS 12.4 KiB).  amdgpu_waves_per_eu(4,8): max=8 stops the allocator
//   from squeezing VGPR below 64 (R8: it chose 40 -> gather serialized);
//   min=4 keeps the hard cap at 128 so nothing can be forced to spill.
//
// Phase A (aggregate): wave w owns nodes w*4..w*4+3 sequentially; lane split
//   fg=lane&31 (8 feats, 16B), ks=lane>>5 (2 slots).  4 accumulator banks,
//   garbage-mantissa unpack, shfl_xor(32) fold.  Gather loop VERBATIM R1
//   (scalar u16 list reads -> 4 independent uint4 loads per group).
//   Epilogue writes bf16 rows straight into LDS in MFMA-frag layout with
//   the r^(chunk&15) slot swizzle (conflict-free write and read).
//
// Phase B (gemm): wave w owns feats w*64..+63 (4 f-tiles x 1 m-tile) —
//   R2/R8's verified structure.  wfr (Wt frags) for ft=0 hoisted ABOVE the
//   barrier; out written nontemporal (keeps Xb/Wt L2-resident).
// ---------------------------------------------------------------------------
__global__
__attribute__((amdgpu_flat_work_group_size(256, 256), amdgpu_waves_per_eu(4, 8)))
void agg_gemm_kernel(
        const unsigned short* __restrict__ Xb, const unsigned* __restrict__ cnt,
        const unsigned short* __restrict__ list,
        const unsigned short* __restrict__ Wt,
        const float* __restrict__ bias, float* __restrict__ out) {
    __shared__ __attribute__((aligned(16))) uint4v lstv[NPB * LIST_CAP / 8]; // 4 KiB
    __shared__ int degs[NPB];
    __shared__ __attribute__((aligned(16))) uint4v frag[NPB * GC_F / 8];     // 8 KiB

    const int tid  = threadIdx.x;
    const int w    = tid >> 6;
    const int lane = tid & 63;
    const int b    = blockIdx.x & 7;              // XCD-pinned batch
    const int n0   = (blockIdx.x >> 3) * NPB;     // first node of group

    // stage 16 neighbor lists (4 KiB = 256 x uint4, one per thread) + degrees
    lstv[tid] = ((const uint4v*)(list + (size_t)n0 * LIST_CAP))[tid];
    if (tid < NPB) {
        const unsigned c = cnt[n0 + tid];
        degs[tid] = (int)(c < LIST_CAP ? c : LIST_CAP);
    }
    __syncthreads();

    const unsigned short* lst = (const unsigned short*)lstv;
    const int fg = lane & 31;               // feature group (8 feats, 16B)
    const int ks = lane >> 5;               // neighbor slot 0..1
    const unsigned short* xbase = Xb + ((size_t)b << 20) + fg * 8;

    #pragma unroll 1
    for (int it = 0; it < NPB / 4; ++it) {
        const int t   = w * 4 + it;         // local node 0..15
        const int deg = degs[t];
        const unsigned short* tl = lst + t * LIST_CAP;

        float2v a0[4] = {}, a1[4] = {}, a2[4] = {}, a3[4] = {};
        int k = ks;
        for (; k + 6 < deg; k += 8) {       // VERBATIM R1 gather group
            const unsigned o0 = (unsigned)tl[k]     << 8;
            const unsigned o1 = (unsigned)tl[k + 2] << 8;
            const unsigned o2 = (unsigned)tl[k + 4] << 8;
            const unsigned o3 = (unsigned)tl[k + 6] << 8;
            const uint4v v0 = *(const uint4v*)(xbase + o0);
            const uint4v v1 = *(const uint4v*)(xbase + o1);
            const uint4v v2 = *(const uint4v*)(xbase + o2);
            const uint4v v3 = *(const uint4v*)(xbase + o3);
            #pragma unroll
            for (int e = 0; e < 4; e++) {
                a0[e] += bfpair(v0[e]);
                a1[e] += bfpair(v1[e]);
                a2[e] += bfpair(v2[e]);
                a3[e] += bfpair(v3[e]);
            }
        }
        for (; k < deg; k += 2) {           // singles tail -> bank 0 (as R1)
            const uint4v v0 = *(const uint4v*)(xbase + ((unsigned)tl[k] << 8));
            #pragma unroll
            for (int e = 0; e < 4; e++) a0[e] += bfpair(v0[e]);
        }

        float accv[8];
        #pragma unroll
        for (int e = 0; e < 4; e++) {
            const float2v s = (a0[e] + a1[e]) + (a2[e] + a3[e]);
            accv[2 * e]     = s.x;   // lo bf16 feature (exact)
            accv[2 * e + 1] = s.y;   // hi bf16 feature (garbage-mantissa)
        }
        #pragma unroll
        for (int e = 0; e < 8; e++)
            accv[e] += __shfl_xor(accv[e], 32, 64);   // fold slot 1 -> slot 0

        if (ks == 0) {
            const float inv = 1.0f / ((float)deg + 1e-6f);
            uint4v o;
            #pragma unroll
            for (int e = 0; e < 4; e++) {
                const float s0 = accv[2 * e] * inv;
                const float s1 = accv[2 * e + 1] * inv;
                o[e] = (unsigned)f2bf_rne(s0) | ((unsigned)f2bf_rne(s1) << 16);
            }
            // frag layout: [chunk=fg][slot = row ^ (fg&15)] of 16B units
            frag[fg * 16 + (t ^ (fg & 15))] = o;
        }
    }

    // hoist ft=0 Wt frags above the barrier (no LDS dependency)
    const int r     = lane & 15;
    const int q     = lane >> 4;
    const int fbase = w * 64;                     // wave: 64 output feats
    short8 wfr[8];
    {
        const unsigned short* wp = Wt + (size_t)(fbase + r) * GC_F + q * 8;
        #pragma unroll
        for (int kc = 0; kc < 8; kc++) wfr[kc] = *(const short8*)(wp + kc * 32);
    }
    __syncthreads();

    const size_t orow0 = ((size_t)b << 12) + n0;  // first out row
    const unsigned short* fragb = (const unsigned short*)frag;
    #pragma unroll 1
    for (int ft = 0; ft < 4; ++ft) {
        const int f0 = fbase + ft * 16;
        const float4v bv = *(const float4v*)(bias + f0 + 4 * q);
        short8 afr[8];
        #pragma unroll
        for (int kc = 0; kc < 8; kc++) {
            const int ch = 4 * kc + q;
            afr[kc] = *(const short8*)(fragb + ch * 128 + (r ^ (ch & 15)) * 8);
        }
        float4v acc = {0, 0, 0, 0};
        #pragma unroll
        for (int kc = 0; kc < 8; kc++)
            acc = __builtin_amdgcn_mfma_f32_16x16x32_bf16(
                wfr[kc], afr[kc], acc, 0, 0, 0);
        const float4v res = acc + bv;
        __builtin_nontemporal_store(res,
            (float4v*)(out + (orow0 + r) * GC_F + f0 + 4 * q));
        if (ft < 3) {   // reload wfr for next f-tile (after last use)
            const unsigned short* wp = Wt + (size_t)(f0 + 16 + r) * GC_F + q * 8;
            #pragma unroll
            for (int kc = 0; kc < 8; kc++) wfr[kc] = *(const short8*)(wp + kc * 32);
        }
    }
}

// ---------------------------------------------------------------------------
extern "C" void kernel_launch(void* const* d_in, const int* in_sizes, int n_in,
                              void* d_out, int out_size, void* d_ws, size_t ws_size,
                              hipStream_t stream) {
    const float* x      = (const float*)d_in[0];   // (8, 4096, 256)
    const int*   ei     = (const int*)d_in[1];     // (2, 131072)
    const float* weight = (const float*)d_in[2];   // (256, 256)
    const float* bias   = (const float*)d_in[3];   // (256,)
    float*       out    = (float*)d_out;           // (8, 4096, 256)

    // ws layout (~19.1 MiB):
    //   [ Xb 16Mi ][ Wt 128Ki ][ mask 2Mi ][ cnt 16Ki ][ list 1Mi ]
    char* p = (char*)d_ws;
    unsigned short* Xb   = (unsigned short*)p;             p += (size_t)GC_M * GC_F * 2;
    unsigned short* Wt   = (unsigned short*)p;             p += (size_t)GC_F * GC_F * 2;
    unsigned*       mask = (unsigned*)p;                   p += (size_t)GC_N * MASK_WPR * 4;
    unsigned*       cnt  = (unsigned*)p;                   p += (size_t)GC_N * 4;
    unsigned short* list = (unsigned short*)p;

    prep_kernel<<<4481, 256, 0, stream>>>(x, weight, Xb, Wt, mask, cnt);

    build_list_kernel<<<(GC_E + 255) / 256, 256, 0, stream>>>(ei, mask, cnt, list);

    agg_gemm_kernel<<<GC_M / NPB, 256, 0, stream>>>(
        Xb, cnt, list, Wt, bias, out);
}

// Round 11
// 160.548 us; speedup vs baseline: 1.0028x; 1.0027x over previous
//
#include <hip/hip_runtime.h>
#include <hip/hip_bf16.h>

// B=8, N=4096, F_IN=F_OUT=256, E=131072
// out = (adj_norm @ X) @ W + bias  (reassociated; same math as ref).
// adj[src,dst]=1 (dups collapse), deg = (#distinct nbrs) + 1e-6.
// 3-dispatch pipeline: prep -> build_list -> fused agg+gemm.
// R10: the allocator's empirical rule (R1 vs R8/R9): VGPR budget =
// 512 / (LDS-implied waves/EU); launch_bounds and waves_per_eu attrs are
// IGNORED.  R1 (LDS 25088 -> 6 blocks -> budget 85) kept the body's 60
// VGPR; R8/R9 (LDS 12800 -> 12 blocks -> budget 42) squeezed to 40 and
// serialized the gather.  Fix: NPB=16 geometry (grid 2048) with LDS PADDED
// to exactly 20480 B (frag oversized; accesses untouched) -> implied
// 8 blocks/CU -> budget 512/8 = 64 >= 60 -> no squeeze.  Gives R1's
// 4-in-flight gather body at 32 waves/CU (2x R1 TLP).  Body and phase B
// bit-for-bit R8 (harness-verified, absmax 0.0078125).

#define GC_B     8
#define GC_N     4096
#define GC_F     256
#define GC_E     131072
#define GC_M     (GC_B * GC_N)          // 32768
#define MASK_WPR (GC_N / 32)            // 128 words / row (512 B)
#define LIST_CAP 128                    // deg ~ Poisson(32); P(>=128) ~ 0
#define NPB      16                     // nodes per fused block
#define FRAG_PAD 508                    // pads block LDS to exactly 20480 B

typedef __attribute__((ext_vector_type(8))) short         short8;   // 8 x bf16
typedef __attribute__((ext_vector_type(2))) float         float2v;
typedef __attribute__((ext_vector_type(4))) float         float4v;
typedef __attribute__((ext_vector_type(4))) unsigned int  uint4v;

static __device__ __forceinline__ unsigned short f2bf_rne(float f) {
    unsigned u = __builtin_bit_cast(unsigned, f);
    u += 0x7fffu + ((u >> 16) & 1u);
    return (unsigned short)(u >> 16);
}

// Accumulate a u32 (two packed bf16) into a float2 accumulator with ONE shl +
// ONE pk_add:  .x += exact lo-bf16 (low bits zeroed by shift);
//              .y += hi-bf16 with lo bits as mantissa garbage (<= 2^-7 rel,
//                    same order as bf16 quantization; absmax budget has 6x
//                    headroom vs threshold).
static __device__ __forceinline__ float2v bfpair(unsigned v) {
    return (float2v){__builtin_bit_cast(float, v << 16),
                     __builtin_bit_cast(float, v)};
}

// ---------------------------------------------------------------------------
// Kernel 1: prep — fused independent setup, block-role split:
//   [0,4096)    : X fp32 -> Xb bf16 (8 elems/thread, 16B stores)
//   [4096,4352) : Wt[n][k] = bf16(W[k][n])
//   [4352,4480) : zero mask (2 MiB)
//   [4480]      : zero cnt  (16 KiB)
// ---------------------------------------------------------------------------
__global__ __launch_bounds__(256) void prep_kernel(
        const float* __restrict__ X, const float* __restrict__ W,
        unsigned short* __restrict__ Xb, unsigned short* __restrict__ Wt,
        unsigned* __restrict__ mask, unsigned* __restrict__ cnt) {
    const int blk = blockIdx.x;
    const int t   = threadIdx.x;
    if (blk < 4096) {
        const size_t i = ((size_t)blk * 256 + t) * 8;
        const float4v v0 = *(const float4v*)(X + i);
        const float4v v1 = *(const float4v*)(X + i + 4);
        union { unsigned short h[8]; short8 s; } u;
        u.h[0] = f2bf_rne(v0[0]); u.h[1] = f2bf_rne(v0[1]);
        u.h[2] = f2bf_rne(v0[2]); u.h[3] = f2bf_rne(v0[3]);
        u.h[4] = f2bf_rne(v1[0]); u.h[5] = f2bf_rne(v1[1]);
        u.h[6] = f2bf_rne(v1[2]); u.h[7] = f2bf_rne(v1[3]);
        *(short8*)(Xb + i) = u.s;
    } else if (blk < 4352) {
        const int n = blk - 4096;
        Wt[n * GC_F + t] = f2bf_rne(W[t * GC_F + n]);
    } else if (blk < 4480) {
        const size_t base = ((size_t)(blk - 4352) * 256 + t) * 4;
        const uint4v z = {0, 0, 0, 0};
        #pragma unroll
        for (int j = 0; j < 4; j++) ((uint4v*)mask)[base + j] = z;
    } else {
        const uint4v z = {0, 0, 0, 0};
        #pragma unroll
        for (int j = 0; j < 4; j++) ((uint4v*)cnt)[(size_t)t * 4 + j] = z;
    }
}

// ---------------------------------------------------------------------------
// Kernel 2: dedup + list build in ONE pass (atomicOr old value: first setter
// of a bit appends). List order nondeterministic; fp32 reorder is ulp-noise.
// ---------------------------------------------------------------------------
__global__ void build_list_kernel(const int* __restrict__ ei,
                                  unsigned* __restrict__ mask,
                                  unsigned* __restrict__ cnt,
                                  unsigned short* __restrict__ list) {
    const int e = blockIdx.x * blockDim.x + threadIdx.x;
    if (e < GC_E) {
        const int s = ei[e];
        const int d = ei[GC_E + e];
        const unsigned bit = 1u << (d & 31);
        const unsigned old = atomicOr(&mask[s * MASK_WPR + (d >> 5)], bit);
        if (!(old & bit)) {
            const unsigned p = atomicAdd(&cnt[s], 1u);
            if (p < LIST_CAP) list[s * LIST_CAP + p] = (unsigned short)d;
        }
    }
}

// ---------------------------------------------------------------------------
// Kernel 3: FUSED aggregate + gemm.  Block = 16 nodes of ONE batch.
//   grid 2048 = 8 b (XCD-pinned, blk&7) x 256 node-groups; LDS padded to
//   20480 B -> allocator targets 163840/20480 = 8 blocks/CU = 8 waves/EU
//   -> VGPR budget 512/8 = 64 -> the 60-VGPR R1 gather body survives
//   (R8/R9 proved budget 42 serializes it).  32 waves/CU = 2x R1 TLP.
//
// Phase A (aggregate): wave w owns nodes w*4..w*4+3 sequentially; lane split
//   fg=lane&31 (8 feats, 16B), ks=lane>>5 (2 slots).  4 accumulator banks,
//   garbage-mantissa unpack, shfl_xor(32) fold.  Gather loop VERBATIM R1
//   (scalar u16 list reads -> 4 independent uint4 loads per group).
//   Epilogue writes bf16 rows straight into LDS in MFMA-frag layout with
//   the r^(chunk&15) slot swizzle (conflict-free write and read).
//
// Phase B (gemm): wave w owns feats w*64..+63 (4 f-tiles x 1 m-tile) —
//   R2/R8's verified structure.  wfr (Wt frags) for ft=0 hoisted ABOVE the
//   barrier; out written nontemporal (keeps Xb/Wt L2-resident).
// ---------------------------------------------------------------------------
__global__ __launch_bounds__(256, 4) void agg_gemm_kernel(
        const unsigned short* __restrict__ Xb, const unsigned* __restrict__ cnt,
        const unsigned short* __restrict__ list,
        const unsigned short* __restrict__ Wt,
        const float* __restrict__ bias, float* __restrict__ out) {
    __shared__ __attribute__((aligned(16))) uint4v lstv[NPB * LIST_CAP / 8]; // 4 KiB
    __shared__ int degs[NPB];
    // frag used: [0, 512) uint4v.  FRAG_PAD oversizes the allocation so the
    // block's total LDS is exactly 20480 B (see header comment) — the pad is
    // never accessed; AMDGPU LDS lowering allocates the declared size.
    __shared__ __attribute__((aligned(16))) uint4v frag[NPB * GC_F / 8 + FRAG_PAD];

    const int tid  = threadIdx.x;
    const int w    = tid >> 6;
    const int lane = tid & 63;
    const int b    = blockIdx.x & 7;              // XCD-pinned batch
    const int n0   = (blockIdx.x >> 3) * NPB;     // first node of group

    // stage 16 neighbor lists (4 KiB = 256 x uint4, one per thread) + degrees
    lstv[tid] = ((const uint4v*)(list + (size_t)n0 * LIST_CAP))[tid];
    if (tid < NPB) {
        const unsigned c = cnt[n0 + tid];
        degs[tid] = (int)(c < LIST_CAP ? c : LIST_CAP);
    }
    __syncthreads();

    const unsigned short* lst = (const unsigned short*)lstv;
    const int fg = lane & 31;               // feature group (8 feats, 16B)
    const int ks = lane >> 5;               // neighbor slot 0..1
    const unsigned short* xbase = Xb + ((size_t)b << 20) + fg * 8;

    #pragma unroll 1
    for (int it = 0; it < NPB / 4; ++it) {
        const int t   = w * 4 + it;         // local node 0..15
        const int deg = degs[t];
        const unsigned short* tl = lst + t * LIST_CAP;

        float2v a0[4] = {}, a1[4] = {}, a2[4] = {}, a3[4] = {};
        int k = ks;
        for (; k + 6 < deg; k += 8) {       // VERBATIM R1 gather group
            const unsigned o0 = (unsigned)tl[k]     << 8;
            const unsigned o1 = (unsigned)tl[k + 2] << 8;
            const unsigned o2 = (unsigned)tl[k + 4] << 8;
            const unsigned o3 = (unsigned)tl[k + 6] << 8;
            const uint4v v0 = *(const uint4v*)(xbase + o0);
            const uint4v v1 = *(const uint4v*)(xbase + o1);
            const uint4v v2 = *(const uint4v*)(xbase + o2);
            const uint4v v3 = *(const uint4v*)(xbase + o3);
            #pragma unroll
            for (int e = 0; e < 4; e++) {
                a0[e] += bfpair(v0[e]);
                a1[e] += bfpair(v1[e]);
                a2[e] += bfpair(v2[e]);
                a3[e] += bfpair(v3[e]);
            }
        }
        for (; k < deg; k += 2) {           // singles tail -> bank 0 (as R1)
            const uint4v v0 = *(const uint4v*)(xbase + ((unsigned)tl[k] << 8));
            #pragma unroll
            for (int e = 0; e < 4; e++) a0[e] += bfpair(v0[e]);
        }

        float accv[8];
        #pragma unroll
        for (int e = 0; e < 4; e++) {
            const float2v s = (a0[e] + a1[e]) + (a2[e] + a3[e]);
            accv[2 * e]     = s.x;   // lo bf16 feature (exact)
            accv[2 * e + 1] = s.y;   // hi bf16 feature (garbage-mantissa)
        }
        #pragma unroll
        for (int e = 0; e < 8; e++)
            accv[e] += __shfl_xor(accv[e], 32, 64);   // fold slot 1 -> slot 0

        if (ks == 0) {
            const float inv = 1.0f / ((float)deg + 1e-6f);
            uint4v o;
            #pragma unroll
            for (int e = 0; e < 4; e++) {
                const float s0 = accv[2 * e] * inv;
                const float s1 = accv[2 * e + 1] * inv;
                o[e] = (unsigned)f2bf_rne(s0) | ((unsigned)f2bf_rne(s1) << 16);
            }
            // frag layout: [chunk=fg][slot = row ^ (fg&15)] of 16B units
            frag[fg * 16 + (t ^ (fg & 15))] = o;
        }
    }

    // hoist ft=0 Wt frags above the barrier (no LDS dependency)
    const int r     = lane & 15;
    const int q     = lane >> 4;
    const int fbase = w * 64;                     // wave: 64 output feats
    short8 wfr[8];
    {
        const unsigned short* wp = Wt + (size_t)(fbase + r) * GC_F + q * 8;
        #pragma unroll
        for (int kc = 0; kc < 8; kc++) wfr[kc] = *(const short8*)(wp + kc * 32);
    }
    __syncthreads();

    const size_t orow0 = ((size_t)b << 12) + n0;  // first out row
    const unsigned short* fragb = (const unsigned short*)frag;
    #pragma unroll 1
    for (int ft = 0; ft < 4; ++ft) {
        const int f0 = fbase + ft * 16;
        const float4v bv = *(const float4v*)(bias + f0 + 4 * q);
        short8 afr[8];
        #pragma unroll
        for (int kc = 0; kc < 8; kc++) {
            const int ch = 4 * kc + q;
            afr[kc] = *(const short8*)(fragb + ch * 128 + (r ^ (ch & 15)) * 8);
        }
        float4v acc = {0, 0, 0, 0};
        #pragma unroll
        for (int kc = 0; kc < 8; kc++)
            acc = __builtin_amdgcn_mfma_f32_16x16x32_bf16(
                wfr[kc], afr[kc], acc, 0, 0, 0);
        const float4v res = acc + bv;
        __builtin_nontemporal_store(res,
            (float4v*)(out + (orow0 + r) * GC_F + f0 + 4 * q));
        if (ft < 3) {   // reload wfr for next f-tile (after last use)
            const unsigned short* wp = Wt + (size_t)(f0 + 16 + r) * GC_F + q * 8;
            #pragma unroll
            for (int kc = 0; kc < 8; kc++) wfr[kc] = *(const short8*)(wp + kc * 32);
        }
    }
}

// ---------------------------------------------------------------------------
extern "C" void kernel_launch(void* const* d_in, const int* in_sizes, int n_in,
                              void* d_out, int out_size, void* d_ws, size_t ws_size,
                              hipStream_t stream) {
    const float* x      = (const float*)d_in[0];   // (8, 4096, 256)
    const int*   ei     = (const int*)d_in[1];     // (2, 131072)
    const float* weight = (const float*)d_in[2];   // (256, 256)
    const float* bias   = (const float*)d_in[3];   // (256,)
    float*       out    = (float*)d_out;           // (8, 4096, 256)

    // ws layout (~19.1 MiB):
    //   [ Xb 16Mi ][ Wt 128Ki ][ mask 2Mi ][ cnt 16Ki ][ list 1Mi ]
    char* p = (char*)d_ws;
    unsigned short* Xb   = (unsigned short*)p;             p += (size_t)GC_M * GC_F * 2;
    unsigned short* Wt   = (unsigned short*)p;             p += (size_t)GC_F * GC_F * 2;
    unsigned*       mask = (unsigned*)p;                   p += (size_t)GC_N * MASK_WPR * 4;
    unsigned*       cnt  = (unsigned*)p;                   p += (size_t)GC_N * 4;
    unsigned short* list = (unsigned short*)p;

    prep_kernel<<<4481, 256, 0, stream>>>(x, weight, Xb, Wt, mask, cnt);

    build_list_kernel<<<(GC_E + 255) / 256, 256, 0, stream>>>(ei, mask, cnt, list);

    agg_gemm_kernel<<<GC_M / NPB, 256, 0, stream>>>(
        Xb, cnt, list, Wt, bias, out);
}

// Round 12
// 146.080 us; speedup vs baseline: 1.1021x; 1.0990x over previous
//
#include <hip/hip_runtime.h>
#include <hip/hip_bf16.h>

// B=8, N=4096, F_IN=F_OUT=256, E=131072
// out = (adj_norm @ X) @ W + bias  (reassociated; same math as ref).
// adj[src,dst]=1 (dups collapse), deg = (#distinct nbrs) + 1e-6.
// 3-dispatch pipeline: prep -> build_list -> fused agg+gemm.
// R11: occupancy/MLP axis closed after 6 falsifications (R2-R10): the
// allocator pins this body at 40 VGPR whenever NPB<32 regardless of LDS
// (R10: padded LDS honored, VGPR unchanged).  Revert to the proven R1
// geometry (NPB=32, agg 47.2us).  NEW: XCD-align prep's Xb writes with
// agg's reads.  Previously prep blocks were round-robin over XCDs, so
// batch b's 2MB slice was written by all 8 XCDs; after prep's kernel-end
// writeback, agg's XCD-pinned gathers miss local L2 and pay L3 latency
// (~600-900cy) on the critical chain.  Remap: XCD k (blk&7) converts
// batch k's slice -> write-allocate in local L2 -> writeback leaves clean
// resident lines -> agg gathers become local-L2 hits (~220cy).  Values
// and the entire agg kernel are bit-for-bit the round-2-verified ones.

#define GC_B     8
#define GC_N     4096
#define GC_F     256
#define GC_E     131072
#define GC_M     (GC_B * GC_N)          // 32768
#define MASK_WPR (GC_N / 32)            // 128 words / row (512 B)
#define LIST_CAP 128                    // deg ~ Poisson(32); P(>=128) ~ 0
#define NPB      32                     // nodes per fused block

typedef __attribute__((ext_vector_type(8))) short         short8;   // 8 x bf16
typedef __attribute__((ext_vector_type(2))) float         float2v;
typedef __attribute__((ext_vector_type(4))) float         float4v;
typedef __attribute__((ext_vector_type(4))) unsigned int  uint4v;

static __device__ __forceinline__ unsigned short f2bf_rne(float f) {
    unsigned u = __builtin_bit_cast(unsigned, f);
    u += 0x7fffu + ((u >> 16) & 1u);
    return (unsigned short)(u >> 16);
}

// Accumulate a u32 (two packed bf16) into a float2 accumulator with ONE shl +
// ONE pk_add:  .x += exact lo-bf16 (low bits zeroed by shift);
//              .y += hi-bf16 with lo bits as mantissa garbage (<= 2^-7 rel,
//                    same order as bf16 quantization; absmax budget has 6x
//                    headroom vs threshold).
static __device__ __forceinline__ float2v bfpair(unsigned v) {
    return (float2v){__builtin_bit_cast(float, v << 16),
                     __builtin_bit_cast(float, v)};
}

// ---------------------------------------------------------------------------
// Kernel 1: prep — fused independent setup, block-role split:
//   [0,4096)    : X fp32 -> Xb bf16 (8 elems/thread, 16B stores).
//                 XCD-ALIGNED: blk&7 = batch (matches agg's XCD pinning),
//                 blk>>3 = 2048-elem chunk within the batch.  Each XCD
//                 writes only its own batch's 2MB slice -> lines stay
//                 resident-clean in that XCD's L2 for the gather kernel.
//   [4096,4352) : Wt[n][k] = bf16(W[k][n])
//   [4352,4480) : zero mask (2 MiB)
//   [4480]      : zero cnt  (16 KiB)
// ---------------------------------------------------------------------------
__global__ __launch_bounds__(256) void prep_kernel(
        const float* __restrict__ X, const float* __restrict__ W,
        unsigned short* __restrict__ Xb, unsigned short* __restrict__ Wt,
        unsigned* __restrict__ mask, unsigned* __restrict__ cnt) {
    const int blk = blockIdx.x;
    const int t   = threadIdx.x;
    if (blk < 4096) {
        const int bb = blk & 7;                   // batch == XCD (agg pinning)
        const int ch = blk >> 3;                  // chunk 0..511 within batch
        const size_t i = ((size_t)bb << 20) + (size_t)ch * 2048 + (size_t)t * 8;
        const float4v v0 = *(const float4v*)(X + i);
        const float4v v1 = *(const float4v*)(X + i + 4);
        union { unsigned short h[8]; short8 s; } u;
        u.h[0] = f2bf_rne(v0[0]); u.h[1] = f2bf_rne(v0[1]);
        u.h[2] = f2bf_rne(v0[2]); u.h[3] = f2bf_rne(v0[3]);
        u.h[4] = f2bf_rne(v1[0]); u.h[5] = f2bf_rne(v1[1]);
        u.h[6] = f2bf_rne(v1[2]); u.h[7] = f2bf_rne(v1[3]);
        *(short8*)(Xb + i) = u.s;
    } else if (blk < 4352) {
        const int n = blk - 4096;
        Wt[n * GC_F + t] = f2bf_rne(W[t * GC_F + n]);
    } else if (blk < 4480) {
        const size_t base = ((size_t)(blk - 4352) * 256 + t) * 4;
        const uint4v z = {0, 0, 0, 0};
        #pragma unroll
        for (int j = 0; j < 4; j++) ((uint4v*)mask)[base + j] = z;
    } else {
        const uint4v z = {0, 0, 0, 0};
        #pragma unroll
        for (int j = 0; j < 4; j++) ((uint4v*)cnt)[(size_t)t * 4 + j] = z;
    }
}

// ---------------------------------------------------------------------------
// Kernel 2: dedup + list build in ONE pass (atomicOr old value: first setter
// of a bit appends). List order nondeterministic; fp32 reorder is ulp-noise.
// ---------------------------------------------------------------------------
__global__ void build_list_kernel(const int* __restrict__ ei,
                                  unsigned* __restrict__ mask,
                                  unsigned* __restrict__ cnt,
                                  unsigned short* __restrict__ list) {
    const int e = blockIdx.x * blockDim.x + threadIdx.x;
    if (e < GC_E) {
        const int s = ei[e];
        const int d = ei[GC_E + e];
        const unsigned bit = 1u << (d & 31);
        const unsigned old = atomicOr(&mask[s * MASK_WPR + (d >> 5)], bit);
        if (!(old & bit)) {
            const unsigned p = atomicAdd(&cnt[s], 1u);
            if (p < LIST_CAP) list[s * LIST_CAP + p] = (unsigned short)d;
        }
    }
}

// ---------------------------------------------------------------------------
// Kernel 3: FUSED aggregate + gemm.  Block = 32 nodes of ONE batch.
//   grid 1024 = 8 b (XCD-pinned, blk&7) x 128 node-groups; 4 blocks/CU.
//   Bit-for-bit the round-2-verified kernel (agg 47.2us, absmax 0.0078125).
//
// Phase A (aggregate): wave w owns nodes w*8..w*8+7 sequentially; lane split
//   fg=lane&31 (8 feats, 16B), ks=lane>>5 (2 slots).  4 accumulator banks,
//   garbage-mantissa unpack, shfl_xor(32) fold.  Epilogue writes bf16 rows
//   straight into LDS in MFMA-frag layout with the r^(chunk&15) swizzle.
//
// Phase B (gemm): wave w owns feats w*64..+63 (4 f-tiles x 2 m-tiles).
//   wfr (Wt frags) for ft=0 hoisted ABOVE the barrier; out nontemporal.
// ---------------------------------------------------------------------------
__global__ __launch_bounds__(256, 4) void agg_gemm_kernel(
        const unsigned short* __restrict__ Xb, const unsigned* __restrict__ cnt,
        const unsigned short* __restrict__ list,
        const unsigned short* __restrict__ Wt,
        const float* __restrict__ bias, float* __restrict__ out) {
    __shared__ __attribute__((aligned(16))) uint4v lstv[NPB * LIST_CAP / 8]; // 8 KiB
    __shared__ int degs[NPB];
    __shared__ __attribute__((aligned(16))) uint4v frag[NPB * GC_F / 8];     // 16 KiB

    const int tid  = threadIdx.x;
    const int w    = tid >> 6;
    const int lane = tid & 63;
    const int b    = blockIdx.x & 7;              // XCD-pinned batch
    const int n0   = (blockIdx.x >> 3) * NPB;     // first node of group

    // stage 32 neighbor lists (8 KiB) + degrees
    {
        const uint4v* src = (const uint4v*)(list + (size_t)n0 * LIST_CAP);
        lstv[tid]       = src[tid];
        lstv[tid + 256] = src[tid + 256];
    }
    if (tid < NPB) {
        const unsigned c = cnt[n0 + tid];
        degs[tid] = (int)(c < LIST_CAP ? c : LIST_CAP);
    }
    __syncthreads();

    const unsigned short* lst = (const unsigned short*)lstv;
    const int fg = lane & 31;               // feature group (8 feats, 16B)
    const int ks = lane >> 5;               // neighbor slot 0..1
    const unsigned short* xbase = Xb + ((size_t)b << 20) + fg * 8;

    #pragma unroll 1
    for (int it = 0; it < 8; ++it) {
        const int t   = w * 8 + it;         // local node 0..31
        const int deg = degs[t];
        const unsigned short* tl = lst + t * LIST_CAP;

        float2v a0[4] = {}, a1[4] = {}, a2[4] = {}, a3[4] = {};
        int k = ks;
        for (; k + 6 < deg; k += 8) {
            const unsigned o0 = (unsigned)tl[k]     << 8;
            const unsigned o1 = (unsigned)tl[k + 2] << 8;
            const unsigned o2 = (unsigned)tl[k + 4] << 8;
            const unsigned o3 = (unsigned)tl[k + 6] << 8;
            const uint4v v0 = *(const uint4v*)(xbase + o0);
            const uint4v v1 = *(const uint4v*)(xbase + o1);
            const uint4v v2 = *(const uint4v*)(xbase + o2);
            const uint4v v3 = *(const uint4v*)(xbase + o3);
            #pragma unroll
            for (int e = 0; e < 4; e++) {
                a0[e] += bfpair(v0[e]);
                a1[e] += bfpair(v1[e]);
                a2[e] += bfpair(v2[e]);
                a3[e] += bfpair(v3[e]);
            }
        }
        for (; k < deg; k += 2) {           // singles tail -> bank 0
            const uint4v v0 = *(const uint4v*)(xbase + ((unsigned)tl[k] << 8));
            #pragma unroll
            for (int e = 0; e < 4; e++) a0[e] += bfpair(v0[e]);
        }

        float accv[8];
        #pragma unroll
        for (int e = 0; e < 4; e++) {
            const float2v s = (a0[e] + a1[e]) + (a2[e] + a3[e]);
            accv[2 * e]     = s.x;   // lo bf16 feature (exact)
            accv[2 * e + 1] = s.y;   // hi bf16 feature (garbage-mantissa)
        }
        #pragma unroll
        for (int e = 0; e < 8; e++)
            accv[e] += __shfl_xor(accv[e], 32, 64);   // fold slot 1 -> slot 0

        if (ks == 0) {
            const float inv = 1.0f / ((float)deg + 1e-6f);
            uint4v o;
            #pragma unroll
            for (int e = 0; e < 4; e++) {
                const float s0 = accv[2 * e] * inv;
                const float s1 = accv[2 * e + 1] * inv;
                o[e] = (unsigned)f2bf_rne(s0) | ((unsigned)f2bf_rne(s1) << 16);
            }
            // frag layout: [mt][chunk=fg][slot = r ^ (fg&15)] of 16B units
            const int mt = t >> 4, r = t & 15;
            frag[mt * 512 + fg * 16 + (r ^ (fg & 15))] = o;
        }
    }

    // hoist ft=0 Wt frags above the barrier (no LDS dependency)
    const int r     = lane & 15;
    const int q     = lane >> 4;
    const int fbase = w * 64;                     // wave: 64 output feats
    short8 wfr[8];
    {
        const unsigned short* wp = Wt + (size_t)(fbase + r) * GC_F + q * 8;
        #pragma unroll
        for (int kc = 0; kc < 8; kc++) wfr[kc] = *(const short8*)(wp + kc * 32);
    }
    __syncthreads();

    const size_t orow0 = ((size_t)b << 12) + n0;  // first out row
    const unsigned short* fragb = (const unsigned short*)frag;
    #pragma unroll 1
    for (int ft = 0; ft < 4; ++ft) {
        const int f0 = fbase + ft * 16;
        const float4v bv = *(const float4v*)(bias + f0 + 4 * q);
        #pragma unroll
        for (int mt = 0; mt < 2; mt++) {
            short8 afr[8];
            #pragma unroll
            for (int kc = 0; kc < 8; kc++) {
                const int ch = 4 * kc + q;
                afr[kc] = *(const short8*)(fragb + mt * 4096 + ch * 128 +
                                           (r ^ (ch & 15)) * 8);
            }
            float4v acc = {0, 0, 0, 0};
            #pragma unroll
            for (int kc = 0; kc < 8; kc++)
                acc = __builtin_amdgcn_mfma_f32_16x16x32_bf16(
                    wfr[kc], afr[kc], acc, 0, 0, 0);
            const float4v res = acc + bv;
            __builtin_nontemporal_store(res,
                (float4v*)(out + (orow0 + mt * 16 + r) * GC_F + f0 + 4 * q));
        }
        if (ft < 3) {   // reload wfr for next f-tile (after last use)
            const unsigned short* wp = Wt + (size_t)(f0 + 16 + r) * GC_F + q * 8;
            #pragma unroll
            for (int kc = 0; kc < 8; kc++) wfr[kc] = *(const short8*)(wp + kc * 32);
        }
    }
}

// ---------------------------------------------------------------------------
extern "C" void kernel_launch(void* const* d_in, const int* in_sizes, int n_in,
                              void* d_out, int out_size, void* d_ws, size_t ws_size,
                              hipStream_t stream) {
    const float* x      = (const float*)d_in[0];   // (8, 4096, 256)
    const int*   ei     = (const int*)d_in[1];     // (2, 131072)
    const float* weight = (const float*)d_in[2];   // (256, 256)
    const float* bias   = (const float*)d_in[3];   // (256,)
    float*       out    = (float*)d_out;           // (8, 4096, 256)

    // ws layout (~19.1 MiB):
    //   [ Xb 16Mi ][ Wt 128Ki ][ mask 2Mi ][ cnt 16Ki ][ list 1Mi ]
    char* p = (char*)d_ws;
    unsigned short* Xb   = (unsigned short*)p;             p += (size_t)GC_M * GC_F * 2;
    unsigned short* Wt   = (unsigned short*)p;             p += (size_t)GC_F * GC_F * 2;
    unsigned*       mask = (unsigned*)p;                   p += (size_t)GC_N * MASK_WPR * 4;
    unsigned*       cnt  = (unsigned*)p;                   p += (size_t)GC_N * 4;
    unsigned short* list = (unsigned short*)p;

    prep_kernel<<<4481, 256, 0, stream>>>(x, weight, Xb, Wt, mask, cnt);

    build_list_kernel<<<(GC_E + 255) / 256, 256, 0, stream>>>(ei, mask, cnt, list);

    agg_gemm_kernel<<<GC_M / NPB, 256, 0, stream>>>(
        Xb, cnt, list, Wt, bias, out);
}